// Round 1
// 393.503 us; speedup vs baseline: 1.0528x; 1.0528x over previous
//
#include <hip/hip_runtime.h>

// Problem: SphereConv2DEXP  — grid_sample(bilinear, zeros, align_corners=False)
// followed by 3x3 conv, stride 3  == implicit GEMM:
//   M = B*Ho*Wo = 4*128*256 = 131072,  N = Cout = 256,  K = Cin*9 = 1152
// x: (4,128,128,256) f32, weight: (256,128,3,3) f32, bias: (256) f32,
// grid: (1,384,768,2) f32, out: (4,256,128,256) f32.
//
// R1: K-dim permuted to k' = ij*128 + ci  (ij-major).  Each BK=32 step has ONE
// fixed ij -> tap table read once/step (kills the 8-way sTW conflicts), and the
// gather walks channels at stride HWp.  Tap rows loaded as float2 (adjacent
// columns xb,xb+1) -> scattered wave-load instrs per CU-step 512 -> 256, which
// is the measured bottleneck (~18.6 cyc per scattered load instr).

#define Hh   128
#define Ww   256
#define HWp  (Hh*Ww)        // 32768 per-channel image size
#define CIN  128
#define COUT 256
#define KTOT 1152
#define NPTS (384*768)      // 294912 grid points
#define BM   128
#define BN   256
#define BK   32
#define NKS  (KTOT/BK)      // 36 K-steps

typedef __attribute__((ext_vector_type(8))) __bf16 bf16x8;
typedef __attribute__((ext_vector_type(4))) float  f32x4;

// ---------------------------------------------------------------------------
// Kernel 1: bilinear tap table. For each grid point store:
//   tI = (row0*W + xb, row1*W + xb)   element offsets of two adjacent-column pairs
//   tW = weights for loaded positions (r0,xb),(r0,xb+1),(r1,xb),(r1,xb+1)
// x0/x1 are always adjacent; out-of-range taps get weight 0 (zero padding).
// ---------------------------------------------------------------------------
__global__ void build_table(const float* __restrict__ grid,
                            int2* __restrict__ tI, float4* __restrict__ tW) {
    int g = blockIdx.x * 256 + threadIdx.x;
    if (g >= NPTS) return;
    int hh = g / 768, ww = g - hh * 768;
    int ho = hh / 3, ii = hh - 3 * ho;
    int wo = ww / 3, jj = ww - 3 * wo;

    float gx = grid[2 * g + 0];
    float gy = grid[2 * g + 1];
    float ix = ((gx + 1.0f) * (float)Ww - 1.0f) * 0.5f;
    float iy = ((gy + 1.0f) * (float)Hh - 1.0f) * 0.5f;
    float x0f = floorf(ix), y0f = floorf(iy);
    int x0 = (int)x0f, y0 = (int)y0f;
    float wx1 = ix - x0f, wx0 = 1.0f - wx1;
    float wy1 = iy - y0f, wy0 = 1.0f - wy1;

    // fold y-validity into row weights; clamp row indices
    float wyt = (y0 >= 0 && y0 < Hh) ? wy0 : 0.0f;
    float wyb = (y0 + 1 >= 0 && y0 + 1 < Hh) ? wy1 : 0.0f;
    int r0 = min(max(y0, 0), Hh - 1);
    int r1 = min(max(y0 + 1, 0), Hh - 1);

    // map x-weights onto the loaded adjacent pair (xb, xb+1)
    int xb; float cw0, cw1;
    if (x0 < 0)            { xb = 0;      cw0 = wx1; cw1 = 0.0f; } // only x1=0 valid
    else if (x0 > Ww - 2)  { xb = Ww - 2; cw0 = 0.0f; cw1 = wx0; } // only x0=W-1 valid
    else                   { xb = x0;     cw0 = wx0; cw1 = wx1; }

    int e = (ho * Ww + wo) * 9 + ii * 3 + jj;   // (sp, ij) order
    tI[e] = make_int2(r0 * Ww + xb, r1 * Ww + xb);
    tW[e] = make_float4(cw0 * wyt, cw1 * wyt, cw0 * wyb, cw1 * wyb);
}

// ---------------------------------------------------------------------------
// Kernel 2: weight f32 -> bf16, retiled as wt[ks][n][kk] with the PERMUTED
// K order: k' = ks*32+kk maps to (ij = k'>>7, ci = k'&127), source w[n][ci*9+ij].
// ---------------------------------------------------------------------------
__global__ void conv_w(const float* __restrict__ w, __bf16* __restrict__ wt) {
    int o = blockIdx.x * 256 + threadIdx.x;   // over NKS*COUT*BK = 294912
    if (o >= NKS * COUT * BK) return;
    int kk = o & (BK - 1);
    int n  = (o >> 5) & (COUT - 1);
    int ks = o >> 13;
    int kp = ks * BK + kk;          // permuted k index
    int ij = kp >> 7;               // 0..8
    int ci = kp & (CIN - 1);        // 0..127
    wt[o] = (__bf16)w[n * KTOT + ci * 9 + ij];
}

// ---------------------------------------------------------------------------
// Kernel 3: fused gather + bf16 MFMA GEMM.
// Block: 512 thr (8 waves, 2x4), tile BM=128 x BN=256, K-step 32.
// Wave tile 64x64 = 4x4 frags of mfma_f32_16x16x32_bf16.
// LDS rows padded to 40 bf16 (80 B) -> 2-way bank aliasing only (free).
// K-step ks covers ij = ks>>2 (fixed), ci = (ks&3)*32 .. +31.
// ---------------------------------------------------------------------------
__global__ __launch_bounds__(512, 4) void sphconv_gemm(
    const float* __restrict__ x, const __bf16* __restrict__ wt,
    const float* __restrict__ bias, const int2* __restrict__ tI,
    const float4* __restrict__ tW, float* __restrict__ out) {

    __shared__ int2   sTI[BM * 9];
    __shared__ float4 sTW[BM * 9];
    __shared__ __align__(16) __bf16 sA[BM * 40];
    __shared__ __align__(16) __bf16 sB[BN * 40];

    const int t   = threadIdx.x;
    const int m0  = blockIdx.x * BM;
    const int b   = m0 >> 15;           // / 32768
    const int sp0 = m0 & (HWp - 1);
    const float* xb_ = x + (size_t)b * (CIN * HWp);

    // stage the per-block tap table (128 sp * 9 taps), reused all 36 K-steps
    for (int e = t; e < BM * 9; e += 512) {
        sTI[e] = tI[sp0 * 9 + e];
        sTW[e] = tW[sp0 * 9 + e];
    }

    const int lane = t & 63;
    const int wid  = t >> 6;
    const int wrow = wid >> 2;          // 0..1 -> m offset 64*wrow
    const int wcol = wid & 3;           // 0..3 -> n offset 64*wcol
    const int quad = lane >> 4;         // 0..3
    const int l16  = lane & 15;

    const int mr_s = t & 127;           // staging row (fixed sp per thread)
    const int kg   = t >> 7;            // 0..3 -> kk base = 8*kg

    f32x4 acc[4][4];
#pragma unroll
    for (int r = 0; r < 4; ++r)
#pragma unroll
        for (int c = 0; c < 4; ++c) {
            f32x4 z = {0.0f, 0.0f, 0.0f, 0.0f};
            acc[r][c] = z;
        }

    __syncthreads();  // table ready

    for (int ks = 0; ks < NKS; ++ks) {
        // ---- stage A: 8 consecutive channels, ONE tap (ij fixed this step) ----
        const int ij  = ks >> 2;
        const int ci0 = (ks & 3) * 32 + kg * 8;
        const int2   o  = sTI[mr_s * 9 + ij];
        const float4 wv = sTW[mr_s * 9 + ij];
        const float* img = xb_ + (size_t)ci0 * HWp;
        bf16x8 av;
#pragma unroll
        for (int j = 0; j < 8; ++j) {
            // adjacent-column pair per row as one 8B load (HW unaligned-ok)
            float2 p0 = *(const float2*)(img + o.x);
            float2 p1 = *(const float2*)(img + o.y);
            av[j] = (__bf16)(p0.x * wv.x + p0.y * wv.y + p1.x * wv.z + p1.y * wv.w);
            img += HWp;
        }
        *(bf16x8*)(&sA[mr_s * 40 + kg * 8]) = av;

        // ---- stage B: contiguous 16 KB chunk, 32 B per thread ----
        {
            const __bf16* src = wt + ks * (COUT * BK) + t * 16;
            bf16x8 v0 = *(const bf16x8*)(src);
            bf16x8 v1 = *(const bf16x8*)(src + 8);
            int n  = t >> 1;
            int kq = (t & 1) * 16;
            *(bf16x8*)(&sB[n * 40 + kq])     = v0;
            *(bf16x8*)(&sB[n * 40 + kq + 8]) = v1;
        }
        __syncthreads();

        // ---- fragments + 16 MFMA ----
        bf16x8 af[4], bfr[4];
#pragma unroll
        for (int r = 0; r < 4; ++r)
            af[r] = *(const bf16x8*)(&sA[(wrow * 64 + r * 16 + l16) * 40 + quad * 8]);
#pragma unroll
        for (int c = 0; c < 4; ++c)
            bfr[c] = *(const bf16x8*)(&sB[(wcol * 64 + c * 16 + l16) * 40 + quad * 8]);
#pragma unroll
        for (int r = 0; r < 4; ++r)
#pragma unroll
            for (int c = 0; c < 4; ++c)
                acc[r][c] = __builtin_amdgcn_mfma_f32_16x16x32_bf16(
                    af[r], bfr[c], acc[r][c], 0, 0, 0);
        __syncthreads();
    }

    // ---- epilogue: D row=(quad*4+i), col=(lane&15)  [m89-verified layout] ----
#pragma unroll
    for (int c = 0; c < 4; ++c) {
        int n = wcol * 64 + c * 16 + l16;
        float bv = bias[n];
        float* outn = out + (((size_t)(b * COUT + n)) << 15) + sp0;
#pragma unroll
        for (int r = 0; r < 4; ++r) {
            int mbase = wrow * 64 + r * 16 + quad * 4;
            float4 v = make_float4(acc[r][c][0] + bv, acc[r][c][1] + bv,
                                   acc[r][c][2] + bv, acc[r][c][3] + bv);
            *(float4*)(&outn[mbase]) = v;   // sp0%128==0, mbase%4==0 -> 16B aligned
        }
    }
}

// ---------------------------------------------------------------------------
extern "C" void kernel_launch(void* const* d_in, const int* in_sizes, int n_in,
                              void* d_out, int out_size, void* d_ws, size_t ws_size,
                              hipStream_t stream) {
    const float* x    = (const float*)d_in[0];
    const float* w    = (const float*)d_in[1];
    const float* bias = (const float*)d_in[2];
    const float* grid = (const float*)d_in[3];
    float* out = (float*)d_out;

    char* ws = (char*)d_ws;
    int2*   tI = (int2*)(ws);                       // 294912 * 8  = 2359296 B
    float4* tW = (float4*)(ws + 2359296);           // 294912 * 16 = 4718592 B
    __bf16* wt = (__bf16*)(ws + 7077888);           // 294912 * 2  =  589824 B

    build_table<<<(NPTS + 255) / 256, 256, 0, stream>>>(grid, tI, tW);
    conv_w<<<(NKS * COUT * BK + 255) / 256, 256, 0, stream>>>(w, wt);
    sphconv_gemm<<<(4 * HWp) / BM, 512, 0, stream>>>(x, wt, bias, tI, tW, out);
}